// Round 12
// baseline (11232.697 us; speedup 1.0000x reference)
//
#include <hip/hip_runtime.h>
#include <hip/hip_bf16.h>

#define B_ 128
#define T_ 512
#define H_ 256
#define G4_ 1024   // 4*H
#define D_ 128

typedef short s8v   __attribute__((ext_vector_type(8)));   // 8 bf16 (as shorts) = MFMA A/B frag
typedef float f32x4 __attribute__((ext_vector_type(4)));
typedef unsigned short u16x4 __attribute__((ext_vector_type(4)));
typedef unsigned short u16x8 __attribute__((ext_vector_type(8)));
typedef unsigned int   u32x4 __attribute__((ext_vector_type(4)));
typedef unsigned short ush;
typedef unsigned long long ull;

// LDS-only barrier: does NOT drain vmcnt (__syncthreads does).
#define BAR_LDS() asm volatile("s_waitcnt lgkmcnt(0)\n\ts_barrier" ::: "memory")

// Agent-scope store (write-through, visible across non-coherent per-XCD L2s).
__device__ __forceinline__ void xstore(ull* p, ull v) {
  __hip_atomic_store(p, v, __ATOMIC_RELAXED, __HIP_MEMORY_SCOPE_AGENT);
}

// ---- static device workspace ----
__device__ __align__(256) ush   g_xw[(size_t)T_ * 2 * B_ * G4_];   // [t][dir][b][hc*4+g]
__device__ __align__(256) ush   g_hseq[(size_t)T_ * B_ * 512];     // [t][b][dir*256+hc]
__device__ __align__(256) float g_hT[B_ * 512];
__device__ __align__(256) unsigned g_tcnt[512];    // hseq[t] readiness (target 16)
__device__ __align__(256) ush   g_wtall[2359296];

__device__ __forceinline__ ush f2b(float f) {
  unsigned u = __builtin_bit_cast(unsigned, f);
  u += 0x7FFFu + ((u >> 16) & 1u);               // RNE
  return (ush)(u >> 16);
}
__device__ __forceinline__ float b2f(ush h) {
  unsigned u = ((unsigned)h) << 16;
  return __builtin_bit_cast(float, u);
}
__device__ __forceinline__ float sigm(float x) {
  x = fminf(15.f, fmaxf(-15.f, x));
  return 1.f / (1.f + __expf(-x));
}
__device__ __forceinline__ float tanh_(float x) {
  x = fminf(8.f, fmaxf(-8.f, x));
  float e = __expf(-2.f * x);
  return (1.f - e) / (1.f + e);
}

// ============================================================
// prep_w: W[k][1024] f32 -> WT[n][k] bf16 (64x64 LDS transpose)
// ============================================================
__global__ __launch_bounds__(256, 4) void prep_w(
    const float* __restrict__ Wf, const float* __restrict__ Wb,
    ush* __restrict__ WTf, ush* __restrict__ WTb, int K)
{
  __shared__ ush tile[64][65];
  const float* W = blockIdx.z ? Wb : Wf;
  ush* WT = blockIdx.z ? WTb : WTf;
  int nt = blockIdx.x & 15, kt = blockIdx.x >> 4;
  int tid = threadIdx.x;
  for (int i = tid; i < 4096; i += 256) {
    int k = i >> 6, n = i & 63;
    tile[k][n] = f2b(W[(size_t)(kt * 64 + k) * 1024 + nt * 64 + n]);
  }
  __syncthreads();
  for (int i = tid; i < 4096; i += 256) {
    int n = i >> 6, k = i & 63;
    WT[(size_t)(nt * 64 + n) * K + kt * 64 + k] = tile[k][n];
  }
}

// ============================================================
// gemm_xw: layer-1 input projection (A row = emb[x[b][t]], K=128)
// ============================================================
__global__ __launch_bounds__(512, 4) void gemm_xw(
    const int* __restrict__ xi, const float* __restrict__ emb,
    const ush* __restrict__ WTf, const ush* __restrict__ WTb)
{
  __shared__ __align__(16) ush A_lds[128 * 72];
  __shared__ __align__(16) ush BT_lds[128 * 72];
  const int tid = threadIdx.x;
  const int lane = tid & 63;
  const int w = tid >> 6;
  const int nb = blockIdx.x;
  const int t = blockIdx.y;
  const int dir = blockIdx.z;
  const ush* WT = dir ? WTb : WTf;

  const f32x4 zero4 = {0.f, 0.f, 0.f, 0.f};
  f32x4 acc[8];
#pragma unroll
  for (int i = 0; i < 8; ++i) acc[i] = zero4;

  const int rowA0 = tid >> 3;
  const int ccA = tid & 7;
  int idx0 = xi[rowA0 * T_ + t];
  int idx1 = xi[(rowA0 + 64) * T_ + t];

  for (int kc = 0; kc < 2; ++kc) {
    __syncthreads();
    {
      const float* s = emb + (size_t)idx0 * D_ + kc * 64 + ccA * 8;
      f32x4 a = *(const f32x4*)s;
      f32x4 b = *(const f32x4*)(s + 4);
      u16x8 v;
      v[0]=f2b(a[0]); v[1]=f2b(a[1]); v[2]=f2b(a[2]); v[3]=f2b(a[3]);
      v[4]=f2b(b[0]); v[5]=f2b(b[1]); v[6]=f2b(b[2]); v[7]=f2b(b[3]);
      *(u16x8*)&A_lds[rowA0 * 72 + ccA * 8] = v;
    }
    {
      const float* s = emb + (size_t)idx1 * D_ + kc * 64 + ccA * 8;
      f32x4 a = *(const f32x4*)s;
      f32x4 b = *(const f32x4*)(s + 4);
      u16x8 v;
      v[0]=f2b(a[0]); v[1]=f2b(a[1]); v[2]=f2b(a[2]); v[3]=f2b(a[3]);
      v[4]=f2b(b[0]); v[5]=f2b(b[1]); v[6]=f2b(b[2]); v[7]=f2b(b[3]);
      *(u16x8*)&A_lds[(rowA0 + 64) * 72 + ccA * 8] = v;
    }
    {
      int n = tid >> 2, k8 = (tid & 3) * 2;
      const ush* src = WT + (size_t)(nb * 128 + n) * 128 + kc * 64 + k8 * 8;
      *(u32x4*)&BT_lds[n * 72 + k8 * 8] = *(const u32x4*)src;
      *(u32x4*)&BT_lds[n * 72 + k8 * 8 + 8] = *(const u32x4*)(src + 8);
    }
    __syncthreads();
#pragma unroll
    for (int kt = 0; kt < 2; ++kt) {
      const int koff = kt * 32 + ((lane >> 4) << 3);
      s8v af = *(const s8v*)&A_lds[(w * 16 + (lane & 15)) * 72 + koff];
#pragma unroll
      for (int nt = 0; nt < 8; ++nt) {
        s8v bf = *(const s8v*)&BT_lds[(nt * 16 + (lane & 15)) * 72 + koff];
        acc[nt] = __builtin_amdgcn_mfma_f32_16x16x32_bf16(af, bf, acc[nt], 0, 0, 0);
      }
    }
  }
  ush* dst = g_xw + ((size_t)t * 2 + dir) * ((size_t)B_ * G4_);
#pragma unroll
  for (int nt = 0; nt < 8; ++nt) {
    int colg = nb * 128 + nt * 16 + (lane & 15);
    int g = colg >> 8, hc = colg & 255;
#pragma unroll
    for (int jj = 0; jj < 4; ++jj) {
      int row = w * 16 + ((lane >> 4) << 2) + jj;
      dst[(size_t)row * 1024 + hc * 4 + g] = f2b(acc[nt][jj]);
    }
  }
}

// ============================================================
// mega (1024 threads = 16 waves):
// blocks [0,16): SELF-CONTAINED LSTM chain. WG owns (slice of 16 batch rows, dir),
//   ALL 256 h-cols, full K=256. h lives in LDS ping-pong; NO cross-WG exchange,
//   NO global ops on the recurrence critical path. One BAR_LDS per step.
//   Wave w owns h-cols [w*16, w*16+16) x 4 gates; bfr[4][8] = 128 VGPR/lane,
//   UNCONDITIONALLY defined + const-indexed (R5/R11 lesson: conditional or
//   runtime-indexed frag arrays spill to scratch -> 2.6x regression).
//   hseq: agent stores + per-step cheap vmcnt(0) drain (ops >=1 step old) +
//   lag-3 certification under the step barrier.
// blocks [16,16+ngemm): persistent layer-2 input GEMM (1024 threads,
//   M=128 x N=128 tile) in hseq-readiness order (tcnt target 16).
// ============================================================
__global__ __launch_bounds__(1024, 1) void mega(
    int layer, const ush* __restrict__ UTf, const ush* __restrict__ UTb,
    const float* __restrict__ bfp, const float* __restrict__ bbp,
    int writeSeq, int ngemm,
    const ush* __restrict__ WT2f, const ush* __restrict__ WT2b)
{
  __shared__ __align__(16) ush smem[2 * 128 * 72];   // 36 KB union (lstm uses 16 KB)
  const int bx = blockIdx.x;
  const int tid = threadIdx.x;
  const int lane = tid & 63;
  const int w = tid >> 6;          // 0..15
  const int l15 = lane & 15;
  const int lq = lane >> 4;

  if (bx < 16) {
    // ================= LSTM role =================
    const int slice = bx & 7;
    const int dir = bx >> 3;
    const ush* UT = dir ? UTb : UTf;
    const float* bias = dir ? bbp : bfp;
    const int mycol = w * 16 + l15;       // wave w owns cols w*16..w*16+15
    const int rowb = slice * 16;
    ush* h0 = smem;   // [2][16*256] ping-pong, XOR-swizzled 8-elem chunks

    // ---- hoist full-K B-fragments (unconditional, const-indexed) ----
    s8v bfr[4][8];
#pragma unroll
    for (int g = 0; g < 4; ++g) {
      const ush* up = UT + (size_t)(g * 256 + mycol) * 256;
#pragma unroll
      for (int kt = 0; kt < 8; ++kt)
        bfr[g][kt] = *(const s8v*)(up + kt * 32 + lq * 8);
    }
    float bias_r[4];
#pragma unroll
    for (int g = 0; g < 4; ++g) bias_r[g] = bias[g * 256 + mycol];

    // zero both h buffers (16 KB)
    {
      ull* z = (ull*)smem;
      z[tid] = 0ull; z[tid + 1024] = 0ull;
    }
    __syncthreads();

    float c_[4] = {0.f, 0.f, 0.f, 0.f};

    // hseq-store decode: thread -> (row, col-group of 4)
    const int srow = tid >> 6;            // 0..15
    const int scg = tid & 63;             // col/4
    const int sc8 = scg >> 1, swo = (scg & 1) * 4;
    const int sswz = ((sc8 ^ srow) & 31) * 8 + swo;

    // xw prefetch for s=0
    u16x4 xv[4];
    {
      int t0 = dir ? (T_ - 1) : 0;
      const ush* xp = g_xw + (((size_t)t0 * 2 + dir) * B_ + rowb) * 1024 + mycol * 4;
#pragma unroll
      for (int j = 0; j < 4; ++j) xv[j] = *(const u16x4*)(xp + (size_t)(lq * 4 + j) * 1024);
    }

    const f32x4 zero4 = {0.f, 0.f, 0.f, 0.f};

    for (int s = 0; s < T_; ++s) {
      const int p = s & 1;
      // ---- A. drain (all ops >=1 step old: cheap) + lag-3 certify + hseq ----
      if (writeSeq) {
        asm volatile("s_waitcnt vmcnt(0)" ::: "memory");
        if (tid == 0 && s >= 3) {
          int td = dir ? (T_ + 2 - s) : (s - 3);
          __hip_atomic_fetch_add(&g_tcnt[td], 1u, __ATOMIC_RELAXED, __HIP_MEMORY_SCOPE_AGENT);
        }
        if (s > 0) {
          const ush* srcl = h0 + p * 4096 + srow * 256 + sswz;
          int tprev = dir ? (T_ - s) : (s - 1);
          xstore((ull*)&g_hseq[((size_t)tprev * B_ + rowb + srow) * 512 + dir * 256 + scg * 4],
                 *(const ull*)srcl);
        }
      }
      // ---- B. xw prefetch for s+1 ----
      u16x4 xn[4];
      {
        int tn = dir ? max(0, T_ - 2 - s) : min(T_ - 1, s + 1);
        const ush* xp = g_xw + (((size_t)tn * 2 + dir) * B_ + rowb) * 1024 + mycol * 4;
#pragma unroll
        for (int j = 0; j < 4; ++j) xn[j] = *(const u16x4*)(xp + (size_t)(lq * 4 + j) * 1024);
      }
      // ---- C. MFMA: z[16 rows, 16 cols x 4 gates], full K=256 from LDS ----
      s8v af[8];
#pragma unroll
      for (int kt = 0; kt < 8; ++kt) {
        int c8 = kt * 4 + lq;
        af[kt] = *(const s8v*)(h0 + p * 4096 + l15 * 256 + ((c8 ^ l15) & 31) * 8);
      }
      f32x4 acc[4];
#pragma unroll
      for (int g = 0; g < 4; ++g) acc[g] = zero4;
#pragma unroll
      for (int kt = 0; kt < 8; ++kt) {
#pragma unroll
        for (int g = 0; g < 4; ++g)
          acc[g] = __builtin_amdgcn_mfma_f32_16x16x32_bf16(af[kt], bfr[g][kt], acc[g], 0, 0, 0);
      }
      // ---- D. activations (rows lq*4+j, col mycol) ----
      ush hv[4];
#pragma unroll
      for (int j = 0; j < 4; ++j) {
        float vi = acc[0][j] + b2f(xv[j][0]) + bias_r[0];
        float vf = acc[1][j] + b2f(xv[j][1]) + bias_r[1];
        float vg = acc[2][j] + b2f(xv[j][2]) + bias_r[2];
        float vo = acc[3][j] + b2f(xv[j][3]) + bias_r[3];
        float ig = sigm(vi), fg = sigm(vf), gg = tanh_(vg), og = sigm(vo);
        float cc = fg * c_[j] + ig * gg;
        c_[j] = cc;
        hv[j] = f2b(og * tanh_(cc));
      }
      // ---- E. write h(s+1) -> LDS buf[p^1] (all 64 lanes, 4 rows each) ----
      {
        int c8o = mycol >> 3, wo = mycol & 7;
        ush* dl = h0 + (p ^ 1) * 4096;
#pragma unroll
        for (int j = 0; j < 4; ++j) {
          int r = lq * 4 + j;
          dl[r * 256 + (((c8o ^ r) & 31) * 8 + wo)] = hv[j];
        }
      }
      BAR_LDS();
#pragma unroll
      for (int j = 0; j < 4; ++j) xv[j] = xn[j];
    }
    // ---- tail ----
    const ush* bufl = h0 + (T_ & 1) * 4096;
    if (writeSeq) {
      {
        const ush* srcl = bufl + srow * 256 + sswz;
        int tlast = dir ? 0 : (T_ - 1);
        xstore((ull*)&g_hseq[((size_t)tlast * B_ + rowb + srow) * 512 + dir * 256 + scg * 4],
               *(const ull*)srcl);
      }
      asm volatile("s_waitcnt vmcnt(0)" ::: "memory");
      __syncthreads();
      if (tid == 0) {
        int ta = dir ? 2 : (T_ - 3);
        int tb = dir ? 1 : (T_ - 2);
        int tc = dir ? 0 : (T_ - 1);
        __hip_atomic_fetch_add(&g_tcnt[ta], 1u, __ATOMIC_RELAXED, __HIP_MEMORY_SCOPE_AGENT);
        __hip_atomic_fetch_add(&g_tcnt[tb], 1u, __ATOMIC_RELAXED, __HIP_MEMORY_SCOPE_AGENT);
        __hip_atomic_fetch_add(&g_tcnt[tc], 1u, __ATOMIC_RELAXED, __HIP_MEMORY_SCOPE_AGENT);
      }
    } else {
      // hT: f32x4 per thread (row srow, cols scg*4..+3)
      const ush* srcl = bufl + srow * 256 + sswz;
      float* dstf = g_hT + (size_t)(rowb + srow) * 512 + dir * 256 + scg * 4;
      f32x4 fv;
#pragma unroll
      for (int j = 0; j < 4; ++j) fv[j] = b2f(srcl[j]);
      *(f32x4*)dstf = fv;
    }
  } else {
    // ================= layer-2 GEMM role (1024 threads, M=128 x N=128) =========
    if (ngemm <= 0) return;
    ush* A_lds = smem;              // [128][72]
    ush* BT_lds = smem + 128 * 72;  // [128][72]
    const int wg = bx - 16;
    const int rowA = tid >> 3;      // 0..127
    const int ccA = tid & 7;
    const int rs = w & 7;           // row strip
    const int ch = w >> 3;          // col half

    for (int u = wg; u < 8192; u += ngemm) {
      int pairIdx = u >> 4, sub = u & 15;
      int nb = sub & 7, gdir = sub >> 3;
      int t = (pairIdx & 1) ? (255 - (pairIdx >> 1)) : (256 + (pairIdx >> 1));
      const ush* WT = gdir ? WT2b : WT2f;
      for (;;) {
        unsigned v = __hip_atomic_load(&g_tcnt[t], __ATOMIC_RELAXED, __HIP_MEMORY_SCOPE_AGENT);
        if (v >= 16u) break;
        __builtin_amdgcn_s_sleep(4);
      }
      const f32x4 zero4 = {0.f, 0.f, 0.f, 0.f};
      f32x4 acc[4];
#pragma unroll
      for (int i = 0; i < 4; ++i) acc[i] = zero4;
      for (int kc = 0; kc < 8; ++kc) {
        __syncthreads();
        {
          const ush* s0 = g_hseq + ((size_t)(t * B_ + rowA)) * 512 + kc * 64 + ccA * 8;
          *(u32x4*)&A_lds[rowA * 72 + ccA * 8] = *(const u32x4*)s0;
          const ush* s1 = WT + (size_t)(nb * 128 + rowA) * 512 + kc * 64 + ccA * 8;
          *(u32x4*)&BT_lds[rowA * 72 + ccA * 8] = *(const u32x4*)s1;
        }
        __syncthreads();
#pragma unroll
        for (int kt = 0; kt < 2; ++kt) {
          const int koff = kt * 32 + (lq << 3);
          s8v af = *(const s8v*)&A_lds[(rs * 16 + l15) * 72 + koff];
#pragma unroll
          for (int nt = 0; nt < 4; ++nt) {
            s8v bf = *(const s8v*)&BT_lds[(ch * 64 + nt * 16 + l15) * 72 + koff];
            acc[nt] = __builtin_amdgcn_mfma_f32_16x16x32_bf16(af, bf, acc[nt], 0, 0, 0);
          }
        }
      }
      ush* dst = g_xw + ((size_t)t * 2 + gdir) * ((size_t)B_ * G4_);
#pragma unroll
      for (int nt = 0; nt < 4; ++nt) {
        int colg = nb * 128 + ch * 64 + nt * 16 + l15;
        int g = colg >> 8, hc = colg & 255;
#pragma unroll
        for (int jj = 0; jj < 4; ++jj) {
          int row = rs * 16 + (lq << 2) + jj;
          dst[(size_t)row * 1024 + hc * 4 + g] = f2b(acc[nt][jj]);
        }
      }
    }
  }
}

// ============================================================
// Dense [128,512]@[512,10] + bias + softmax -> out f32
// ============================================================
__global__ __launch_bounds__(512, 1) void dense_softmax(
    const float* __restrict__ Wd, const float* __restrict__ bd, float* __restrict__ out)
{
  __shared__ float wT[10 * 512];
  __shared__ float part[512 * 10];
  int tid = threadIdx.x;
  for (int i = tid; i < 5120; i += 512) {
    int k = i / 10, j = i - k * 10;
    wT[j * 512 + k] = Wd[i];
  }
  __syncthreads();
  int row = tid >> 2, q = tid & 3;
  float acc[10];
#pragma unroll
  for (int j = 0; j < 10; ++j) acc[j] = 0.f;
  const float* hrow = g_hT + (size_t)row * 512 + q * 128;
  for (int kk = 0; kk < 32; ++kk) {
    f32x4 h4 = *(const f32x4*)(hrow + kk * 4);
#pragma unroll
    for (int j = 0; j < 10; ++j) {
      f32x4 w4 = *(const f32x4*)&wT[j * 512 + q * 128 + kk * 4];
      acc[j] += h4[0] * w4[0] + h4[1] * w4[1] + h4[2] * w4[2] + h4[3] * w4[3];
    }
  }
#pragma unroll
  for (int j = 0; j < 10; ++j) part[tid * 10 + j] = acc[j];
  __syncthreads();
  if (tid < 128) {
    float lg[10];
#pragma unroll
    for (int j = 0; j < 10; ++j)
      lg[j] = bd[j] + part[(tid * 4 + 0) * 10 + j] + part[(tid * 4 + 1) * 10 + j]
                    + part[(tid * 4 + 2) * 10 + j] + part[(tid * 4 + 3) * 10 + j];
    float m = lg[0];
#pragma unroll
    for (int j = 1; j < 10; ++j) m = fmaxf(m, lg[j]);
    float ssum = 0.f;
#pragma unroll
    for (int j = 0; j < 10; ++j) { lg[j] = __expf(lg[j] - m); ssum += lg[j]; }
    float inv = 1.f / ssum;
#pragma unroll
    for (int j = 0; j < 10; ++j) out[tid * 10 + j] = lg[j] * inv;
  }
}

extern "C" void kernel_launch(void* const* d_in, const int* in_sizes, int n_in,
                              void* d_out, int out_size, void* d_ws, size_t ws_size,
                              hipStream_t stream) {
  (void)in_sizes; (void)n_in; (void)d_ws; (void)ws_size; (void)out_size;
  const int* x = (const int*)d_in[0];
  const float* emb = (const float*)d_in[1];
  const float* W1f = (const float*)d_in[2];
  const float* U1f = (const float*)d_in[3];
  const float* b1f = (const float*)d_in[4];
  const float* W1b = (const float*)d_in[5];
  const float* U1b = (const float*)d_in[6];
  const float* b1b = (const float*)d_in[7];
  const float* W2f = (const float*)d_in[8];
  const float* U2f = (const float*)d_in[9];
  const float* b2f = (const float*)d_in[10];
  const float* W2b = (const float*)d_in[11];
  const float* U2b = (const float*)d_in[12];
  const float* b2b = (const float*)d_in[13];
  const float* Wd  = (const float*)d_in[14];
  const float* bd  = (const float*)d_in[15];
  float* out = (float*)d_out;

  void* wt_p = nullptr; void* tc_p = nullptr;
  hipGetSymbolAddress(&wt_p, HIP_SYMBOL(g_wtall));
  hipGetSymbolAddress(&tc_p, HIP_SYMBOL(g_tcnt));
  ush* wt = (ush*)wt_p;
  // counters must start at 0 every launch (graph replays!)
  hipMemsetAsync(tc_p, 0, sizeof(unsigned) * 512, stream);

  ush* wt1f = wt;                 ush* wt1b = wt1f + 131072;   // K=128
  ush* ut1f = wt1b + 131072;      ush* ut1b = ut1f + 262144;   // K=256
  ush* wt2f = ut1b + 262144;      ush* wt2b = wt2f + 524288;   // K=512
  ush* ut2f = wt2b + 524288;      ush* ut2b = ut2f + 262144;   // K=256

  prep_w<<<dim3(32, 1, 2), 256, 0, stream>>>(W1f, W1b, wt1f, wt1b, 128);
  prep_w<<<dim3(64, 1, 2), 256, 0, stream>>>(U1f, U1b, ut1f, ut1b, 256);
  prep_w<<<dim3(128, 1, 2), 256, 0, stream>>>(W2f, W2b, wt2f, wt2b, 512);
  prep_w<<<dim3(64, 1, 2), 256, 0, stream>>>(U2f, U2b, ut2f, ut2b, 256);

  // layer 1 input projection (emb gather, K=128)
  gemm_xw<<<dim3(8, T_, 2), 512, 0, stream>>>(x, emb, wt1f, wt1b);
  // layer 1 recurrence (16 self-contained WGs) + fused layer-2 input GEMM (192 WGs)
  mega<<<208, 1024, 0, stream>>>(0, ut1f, ut1b, b1f, b1b, 1, 192, wt2f, wt2b);
  // layer 2 recurrence (16 WGs)
  mega<<<16, 1024, 0, stream>>>(1, ut2f, ut2b, b2f, b2b, 0, 0, nullptr, nullptr);
  // dense + softmax
  dense_softmax<<<1, 512, 0, stream>>>(Wd, bd, out);
}

// Round 13
// 3221.055 us; speedup vs baseline: 3.4873x; 3.4873x over previous
//
#include <hip/hip_runtime.h>
#include <hip/hip_bf16.h>

#define B_ 128
#define T_ 512
#define H_ 256
#define G4_ 1024   // 4*H
#define D_ 128

typedef short s8v   __attribute__((ext_vector_type(8)));   // 8 bf16 (as shorts) = MFMA A/B frag
typedef float f32x4 __attribute__((ext_vector_type(4)));
typedef unsigned short u16x4 __attribute__((ext_vector_type(4)));
typedef unsigned short u16x8 __attribute__((ext_vector_type(8)));
typedef unsigned int   u32x4 __attribute__((ext_vector_type(4)));
typedef unsigned short ush;
typedef unsigned long long ull;

// LDS-only barrier: does NOT drain vmcnt (__syncthreads does).
#define BAR_LDS() asm volatile("s_waitcnt lgkmcnt(0)\n\ts_barrier" ::: "memory")

// Agent-scope exchange ops (R8-proven correct cross-XCD).
__device__ __forceinline__ void xstore(ull* p, ull v) {
  __hip_atomic_store(p, v, __ATOMIC_RELAXED, __HIP_MEMORY_SCOPE_AGENT);
}
__device__ __forceinline__ ull xload(const ull* p) {
  return __hip_atomic_load(p, __ATOMIC_RELAXED, __HIP_MEMORY_SCOPE_AGENT);
}

// ---- static device workspace ----
__device__ __align__(256) ush   g_xw[(size_t)T_ * 2 * B_ * G4_];   // [t][dir][b][hc*4+g]
__device__ __align__(256) ush   g_hseq[(size_t)T_ * B_ * 512];     // [t][b][dir*256+hc]
// exchange: [slice16][dir2] x regions [p2][nh2] x 512 granules (b64 = 2 bf16 + u32 seq)
__device__ __align__(256) ull   g_hx2[16 * 2 * 2 * 2 * 512];
__device__ __align__(256) float g_hT[B_ * 512];
__device__ __align__(256) unsigned g_tcnt[512];    // hseq[t] readiness (target 64)
__device__ __align__(256) ush   g_wtall[2359296];

__device__ __forceinline__ ush f2b(float f) {
  unsigned u = __builtin_bit_cast(unsigned, f);
  u += 0x7FFFu + ((u >> 16) & 1u);               // RNE
  return (ush)(u >> 16);
}
__device__ __forceinline__ float b2f(ush h) {
  unsigned u = ((unsigned)h) << 16;
  return __builtin_bit_cast(float, u);
}
__device__ __forceinline__ float sigm(float x) {
  x = fminf(15.f, fmaxf(-15.f, x));
  return 1.f / (1.f + __expf(-x));
}
__device__ __forceinline__ float tanh_(float x) {
  x = fminf(8.f, fmaxf(-8.f, x));
  float e = __expf(-2.f * x);
  return (1.f - e) / (1.f + e);
}

// ============================================================
// prep_w: W[k][1024] f32 -> WT[n][k] bf16 (64x64 LDS transpose)
// ============================================================
__global__ __launch_bounds__(256, 4) void prep_w(
    const float* __restrict__ Wf, const float* __restrict__ Wb,
    ush* __restrict__ WTf, ush* __restrict__ WTb, int K)
{
  __shared__ ush tile[64][65];
  const float* W = blockIdx.z ? Wb : Wf;
  ush* WT = blockIdx.z ? WTb : WTf;
  int nt = blockIdx.x & 15, kt = blockIdx.x >> 4;
  int tid = threadIdx.x;
  for (int i = tid; i < 4096; i += 256) {
    int k = i >> 6, n = i & 63;
    tile[k][n] = f2b(W[(size_t)(kt * 64 + k) * 1024 + nt * 64 + n]);
  }
  __syncthreads();
  for (int i = tid; i < 4096; i += 256) {
    int n = i >> 6, k = i & 63;
    WT[(size_t)(nt * 64 + n) * K + kt * 64 + k] = tile[k][n];
  }
}

// ============================================================
// gemm_xw: layer-1 input projection (A row = emb[x[b][t]], K=128)
// ============================================================
__global__ __launch_bounds__(512, 4) void gemm_xw(
    const int* __restrict__ xi, const float* __restrict__ emb,
    const ush* __restrict__ WTf, const ush* __restrict__ WTb)
{
  __shared__ __align__(16) ush A_lds[128 * 72];
  __shared__ __align__(16) ush BT_lds[128 * 72];
  const int tid = threadIdx.x;
  const int lane = tid & 63;
  const int w = tid >> 6;
  const int nb = blockIdx.x;
  const int t = blockIdx.y;
  const int dir = blockIdx.z;
  const ush* WT = dir ? WTb : WTf;

  const f32x4 zero4 = {0.f, 0.f, 0.f, 0.f};
  f32x4 acc[8];
#pragma unroll
  for (int i = 0; i < 8; ++i) acc[i] = zero4;

  const int rowA0 = tid >> 3;
  const int ccA = tid & 7;
  int idx0 = xi[rowA0 * T_ + t];
  int idx1 = xi[(rowA0 + 64) * T_ + t];

  for (int kc = 0; kc < 2; ++kc) {
    __syncthreads();
    {
      const float* s = emb + (size_t)idx0 * D_ + kc * 64 + ccA * 8;
      f32x4 a = *(const f32x4*)s;
      f32x4 b = *(const f32x4*)(s + 4);
      u16x8 v;
      v[0]=f2b(a[0]); v[1]=f2b(a[1]); v[2]=f2b(a[2]); v[3]=f2b(a[3]);
      v[4]=f2b(b[0]); v[5]=f2b(b[1]); v[6]=f2b(b[2]); v[7]=f2b(b[3]);
      *(u16x8*)&A_lds[rowA0 * 72 + ccA * 8] = v;
    }
    {
      const float* s = emb + (size_t)idx1 * D_ + kc * 64 + ccA * 8;
      f32x4 a = *(const f32x4*)s;
      f32x4 b = *(const f32x4*)(s + 4);
      u16x8 v;
      v[0]=f2b(a[0]); v[1]=f2b(a[1]); v[2]=f2b(a[2]); v[3]=f2b(a[3]);
      v[4]=f2b(b[0]); v[5]=f2b(b[1]); v[6]=f2b(b[2]); v[7]=f2b(b[3]);
      *(u16x8*)&A_lds[(rowA0 + 64) * 72 + ccA * 8] = v;
    }
    {
      int n = tid >> 2, k8 = (tid & 3) * 2;
      const ush* src = WT + (size_t)(nb * 128 + n) * 128 + kc * 64 + k8 * 8;
      *(u32x4*)&BT_lds[n * 72 + k8 * 8] = *(const u32x4*)src;
      *(u32x4*)&BT_lds[n * 72 + k8 * 8 + 8] = *(const u32x4*)(src + 8);
    }
    __syncthreads();
#pragma unroll
    for (int kt = 0; kt < 2; ++kt) {
      const int koff = kt * 32 + ((lane >> 4) << 3);
      s8v af = *(const s8v*)&A_lds[(w * 16 + (lane & 15)) * 72 + koff];
#pragma unroll
      for (int nt = 0; nt < 8; ++nt) {
        s8v bf = *(const s8v*)&BT_lds[(nt * 16 + (lane & 15)) * 72 + koff];
        acc[nt] = __builtin_amdgcn_mfma_f32_16x16x32_bf16(af, bf, acc[nt], 0, 0, 0);
      }
    }
  }
  ush* dst = g_xw + ((size_t)t * 2 + dir) * ((size_t)B_ * G4_);
#pragma unroll
  for (int nt = 0; nt < 8; ++nt) {
    int colg = nb * 128 + nt * 16 + (lane & 15);
    int g = colg >> 8, hc = colg & 255;
#pragma unroll
    for (int jj = 0; jj < 4; ++jj) {
      int row = w * 16 + ((lane >> 4) << 2) + jj;
      dst[(size_t)row * 1024 + hc * 4 + g] = f2b(acc[nt][jj]);
    }
  }
}

// ============================================================
// mega: blocks [0,64): persistent LSTM recurrence (M=8/WG, column-pair).
//   R13: POLL PREFETCH — each thread issues its next-step poll load right
//   after the export (partner exports ~simultaneously; load arrives at the
//   coherence point ~RTT later, exactly when data becomes visible). Step-top
//   first-use triggers the waitcnt; only stale lanes enter the (sleep-free)
//   retry loop. Eliminates the guaranteed first-poll miss (~1 RTT/step).
//   512 threads / launch_bounds(512,2) is the ONLY feasible register point:
//   VGPR pool = 512/SIMD (m69), so 2 waves/SIMD -> 256 regs/wave; bfr (128)
//   + state fits (R8: 116 VGPR + AGPRs). 1024-thr blocks cap at 128/wave ->
//   catastrophic spill (R12). Frag arrays unconditional + const-indexed
//   (R5/R11 lessons).
// blocks [64,64+ngemm): persistent layer-2 input GEMM in hseq-readiness order.
// ============================================================
__global__ __launch_bounds__(512, 2) void mega(
    int layer, const ush* __restrict__ UTf, const ush* __restrict__ UTb,
    const float* __restrict__ bfp, const float* __restrict__ bbp,
    int writeSeq, int ngemm,
    const ush* __restrict__ WT2f, const ush* __restrict__ WT2b)
{
  __shared__ __align__(16) ush smem[2 * 128 * 72];   // 36 KB union
  const int bx = blockIdx.x;
  const int tid = threadIdx.x;
  const int lane = tid & 63;
  const int w = tid >> 6;
  const int l15 = lane & 15;
  const int lq = lane >> 4;

  if (bx < 64) {
    // ================= LSTM role =================
    const int slice = bx & 15;
    const int dir = (bx >> 4) & 1;
    const int nh = bx >> 5;
    const ush* UT = dir ? UTb : UTf;
    const float* bias = dir ? bbp : bfp;
    const int mycol = nh * 128 + w * 16 + l15;
    const int rowb = slice * 8;
    const unsigned sbase = (unsigned)(layer * T_);
    ush* h0 = smem;   // [2][16*256] ping-pong, XOR-swizzled; rows 8..15 stay 0

    // ---- hoist U-half B-fragments in two const-indexed arrays ----
    s8v bfrO[4][4], bfrP[4][4];
#pragma unroll
    for (int g = 0; g < 4; ++g) {
      const ush* up = UT + (size_t)(g * 256 + mycol) * 256;
#pragma unroll
      for (int i = 0; i < 4; ++i) {
        bfrO[g][i] = *(const s8v*)(up + (nh * 128 + i * 32) + lq * 8);
        bfrP[g][i] = *(const s8v*)(up + ((nh ^ 1) * 128 + i * 32) + lq * 8);
      }
    }
    float bias_r[4];
#pragma unroll
    for (int g = 0; g < 4; ++g) bias_r[g] = bias[g * 256 + mycol];

    // zero both h buffers (16 KB)
    {
      ull* z = (ull*)smem;
      z[tid] = 0ull; z[tid + 512] = 0ull; z[tid + 1024] = 0ull; z[tid + 1536] = 0ull;
    }
    __syncthreads();

    float c_[4] = {0.f, 0.f, 0.f, 0.f};
    ull* hx_sd = g_hx2 + (size_t)(slice * 2 + dir) * 2048;   // 4 regions x 512 granules

    // importer decode: thread t imports granule t of partner region
    const int w_src = tid >> 6, r_ = tid & 63;
    const int blkc = r_ >> 5, lqs = (r_ >> 4) & 1, l15s = r_ & 15;
    const int col_p = (nh ^ 1) * 128 + w_src * 16 + l15s;
    const int r0c = lqs * 4 + blkc * 2;
    const int c8p = col_p >> 3, wp = col_p & 7;
    const int sw0 = ((c8p ^ r0c) & 31) * 8 + wp;
    const int sw1 = ((c8p ^ (r0c + 1)) & 31) * 8 + wp;
    const int xrow = (lq & 1) * 4;

    // xw prefetch for s=0
    u16x4 xv[4];
    {
      int t0 = dir ? (T_ - 1) : 0;
      const ush* xp = g_xw + (((size_t)t0 * 2 + dir) * B_ + rowb) * 1024 + mycol * 4;
#pragma unroll
      for (int j = 0; j < 4; ++j) xv[j] = *(const u16x4*)(xp + (size_t)(xrow + j) * 1024);
    }

    const f32x4 zero4 = {0.f, 0.f, 0.f, 0.f};
    f32x4 acc[4];
#pragma unroll
    for (int g = 0; g < 4; ++g) acc[g] = zero4;   // own-half contribution for s=0 (h_0=0)
    ull pref = 0;                                 // prefetched poll value for step s

    for (int s = 0; s < T_; ++s) {
      const int p = s & 1;
      // ---- A. import partner half of h_s: check prefetched value first ----
      if (s > 0) {
        const ull* ap = hx_sd + (size_t)(p * 2 + (nh ^ 1)) * 512 + tid;
        unsigned target = sbase + (unsigned)s;
        ull v = pref;               // first use drains vmcnt (incl. aged exports)
        while ((unsigned)(v >> 32) < target) {
          v = xload(ap);            // sleep-free tight retry
        }
        ush* dl = h0 + p * 4096;
        dl[r0c * 256 + sw0] = (ush)v;
        dl[(r0c + 1) * 256 + sw1] = (ush)(v >> 16);
      }
      BAR_LDS();
      // ---- B. certify t(s-2); hseq store for t(s-1) (ages a full step) ----
      if (writeSeq) {
        if (tid == 0 && s >= 2) {
          int td = dir ? (T_ + 1 - s) : (s - 2);
          __hip_atomic_fetch_add(&g_tcnt[td], 1u, __ATOMIC_RELAXED, __HIP_MEMORY_SCOPE_AGENT);
        }
        if (s > 0 && tid < 128) {
          int row8 = tid >> 4, idx = tid & 15;
          int col = nh * 128 + idx * 8;
          int c8 = col >> 3;
          const ush* srcl = h0 + p * 4096 + row8 * 256 + ((c8 ^ row8) & 31) * 8;
          ull lo = *(const ull*)srcl;
          ull hi = *(const ull*)(srcl + 4);
          int tprev = dir ? (T_ - s) : (s - 1);
          ull* dst = (ull*)&g_hseq[((size_t)tprev * B_ + rowb + row8) * 512 + dir * 256 + col];
          xstore(dst, lo);
          xstore(dst + 1, hi);
        }
      }
      // ---- D. partner-half MFMA (4 k-tiles; acc carries own-half from prev step) ----
      {
        s8v afP[4];
#pragma unroll
        for (int i = 0; i < 4; ++i) {
          int c8 = ((nh ^ 1) * 4 + i) * 4 + lq;
          afP[i] = *(const s8v*)(h0 + p * 4096 + l15 * 256 + ((c8 ^ l15) & 31) * 8);
        }
#pragma unroll
        for (int i = 0; i < 4; ++i) {
#pragma unroll
          for (int g = 0; g < 4; ++g)
            acc[g] = __builtin_amdgcn_mfma_f32_16x16x32_bf16(afP[i], bfrP[g][i], acc[g], 0, 0, 0);
        }
      }
      // ---- E. activations ----
      ush hv[4];
#pragma unroll
      for (int j = 0; j < 4; ++j) {
        float vi = acc[0][j] + b2f(xv[j][0]) + bias_r[0];
        float vf = acc[1][j] + b2f(xv[j][1]) + bias_r[1];
        float vg = acc[2][j] + b2f(xv[j][2]) + bias_r[2];
        float vo = acc[3][j] + b2f(xv[j][3]) + bias_r[3];
        float ig = sigm(vi), fg = sigm(vf), gg = tanh_(vg), og = sigm(vo);
        float cc = fg * c_[j] + ig * gg;
        c_[j] = cc;
        hv[j] = f2b(og * tanh_(cc));
      }
      // ---- C. xw prefetch for s+1 ----
      u16x4 xn[4];
      {
        int tn = dir ? max(0, T_ - 2 - s) : min(T_ - 1, s + 1);
        const ush* xp = g_xw + (((size_t)tn * 2 + dir) * B_ + rowb) * 1024 + mycol * 4;
#pragma unroll
        for (int j = 0; j < 4; ++j) xn[j] = *(const u16x4*)(xp + (size_t)(xrow + j) * 1024);
      }
      // ---- F. export: 2 coalescing agent stores per producing lane ----
      if (lq < 2 && s + 1 < T_) {
        ull seqw = ((ull)(sbase + (unsigned)s + 1u)) << 32;
        ull e0 = (ull)hv[0] | ((ull)hv[1] << 16) | seqw;
        ull e1 = (ull)hv[2] | ((ull)hv[3] << 16) | seqw;
        ull* ep = hx_sd + (size_t)((p ^ 1) * 2 + nh) * 512 + w * 64 + lq * 16 + l15;
        xstore(ep, e0);
        xstore(ep + 32, e1);
      }
      // ---- F2. issue next step's poll prefetch (arrives ~when partner data lands) ----
      if (s + 1 < T_) {
        pref = xload(hx_sd + (size_t)((p ^ 1) * 2 + (nh ^ 1)) * 512 + tid);
      }
      // ---- G. own h -> LDS buf[p^1] ----
      if (lq < 2) {
        int c8o = mycol >> 3, wo = mycol & 7;
        ush* dl = h0 + (p ^ 1) * 4096;
#pragma unroll
        for (int j = 0; j < 4; ++j) {
          int r = lq * 4 + j;
          dl[r * 256 + (((c8o ^ r) & 31) * 8 + wo)] = hv[j];
        }
      }
      BAR_LDS();
      // ---- H. own-half MFMA for s+1 (hides prefetch RTT) ----
#pragma unroll
      for (int g = 0; g < 4; ++g) acc[g] = zero4;
      {
        s8v afO[4];
#pragma unroll
        for (int i = 0; i < 4; ++i) {
          int c8 = (nh * 4 + i) * 4 + lq;
          afO[i] = *(const s8v*)(h0 + (p ^ 1) * 4096 + l15 * 256 + ((c8 ^ l15) & 31) * 8);
        }
#pragma unroll
        for (int i = 0; i < 4; ++i) {
#pragma unroll
          for (int g = 0; g < 4; ++g)
            acc[g] = __builtin_amdgcn_mfma_f32_16x16x32_bf16(afO[i], bfrO[g][i], acc[g], 0, 0, 0);
        }
      }
#pragma unroll
      for (int j = 0; j < 4; ++j) xv[j] = xn[j];
    }
    // ---- tail: own cols of final state are in LDS[T&1] ----
    __syncthreads();
    const ush* bufl = h0 + (T_ & 1) * 4096;
    if (writeSeq) {
      if (tid < 128) {
        int row8 = tid >> 4, idx = tid & 15;
        int col = nh * 128 + idx * 8;
        int c8 = col >> 3;
        const ush* srcl = bufl + row8 * 256 + ((c8 ^ row8) & 31) * 8;
        ull lo = *(const ull*)srcl;
        ull hi = *(const ull*)(srcl + 4);
        int tlast = dir ? 0 : (T_ - 1);
        ull* dst = (ull*)&g_hseq[((size_t)tlast * B_ + rowb + row8) * 512 + dir * 256 + col];
        xstore(dst, lo);
        xstore(dst + 1, hi);
      }
      asm volatile("s_waitcnt vmcnt(0)" ::: "memory");
      __syncthreads();
      if (tid == 0) {
        int ta = dir ? 1 : (T_ - 2);
        int tb2 = dir ? 0 : (T_ - 1);
        __hip_atomic_fetch_add(&g_tcnt[ta], 1u, __ATOMIC_RELAXED, __HIP_MEMORY_SCOPE_AGENT);
        __hip_atomic_fetch_add(&g_tcnt[tb2], 1u, __ATOMIC_RELAXED, __HIP_MEMORY_SCOPE_AGENT);
      }
    } else {
      if (tid < 128) {
        int row8 = tid >> 4, idx = tid & 15;
        int col = nh * 128 + idx * 8;
        int c8 = col >> 3;
        const ush* srcl = bufl + row8 * 256 + ((c8 ^ row8) & 31) * 8;
        float* dstf = g_hT + (size_t)(rowb + row8) * 512 + dir * 256 + col;
        f32x4 f0, f1;
#pragma unroll
        for (int j = 0; j < 4; ++j) { f0[j] = b2f(srcl[j]); f1[j] = b2f(srcl[4 + j]); }
        *(f32x4*)dstf = f0;
        *(f32x4*)(dstf + 4) = f1;
      }
    }
  } else {
    // ================= layer-2 GEMM role =================
    if (ngemm <= 0) return;
    ush* A_lds = smem;
    ush* BT_lds = smem + 128 * 72;
    const int wg = bx - 64;
    const int rowA0 = tid >> 3;
    const int ccA = tid & 7;

    for (int u = wg; u < 8192; u += ngemm) {
      int pairIdx = u >> 4, sub = u & 15;
      int nb = sub & 7, gdir = sub >> 3;
      int t = (pairIdx & 1) ? (255 - (pairIdx >> 1)) : (256 + (pairIdx >> 1));
      const ush* WT = gdir ? WT2b : WT2f;
      for (;;) {
        unsigned v = __hip_atomic_load(&g_tcnt[t], __ATOMIC_RELAXED, __HIP_MEMORY_SCOPE_AGENT);
        if (v >= 64u) break;
        __builtin_amdgcn_s_sleep(4);
      }
      const f32x4 zero4 = {0.f, 0.f, 0.f, 0.f};
      f32x4 acc[8];
#pragma unroll
      for (int i = 0; i < 8; ++i) acc[i] = zero4;
      for (int kc = 0; kc < 8; ++kc) {
        __syncthreads();
        {
          const ush* s0 = g_hseq + ((size_t)(t * B_ + rowA0)) * 512 + kc * 64 + ccA * 8;
          *(u32x4*)&A_lds[rowA0 * 72 + ccA * 8] = *(const u32x4*)s0;
          const ush* s1 = g_hseq + ((size_t)(t * B_ + rowA0 + 64)) * 512 + kc * 64 + ccA * 8;
          *(u32x4*)&A_lds[(rowA0 + 64) * 72 + ccA * 8] = *(const u32x4*)s1;
        }
        {
          int n = tid >> 2, k8 = (tid & 3) * 2;
          const ush* src = WT + (size_t)(nb * 128 + n) * 512 + kc * 64 + k8 * 8;
          *(u32x4*)&BT_lds[n * 72 + k8 * 8] = *(const u32x4*)src;
          *(u32x4*)&BT_lds[n * 72 + k8 * 8 + 8] = *(const u32x4*)(src + 8);
        }
        __syncthreads();
#pragma unroll
        for (int kt = 0; kt < 2; ++kt) {
          const int koff = kt * 32 + (lq << 3);
          s8v af = *(const s8v*)&A_lds[(w * 16 + l15) * 72 + koff];
#pragma unroll
          for (int nt = 0; nt < 8; ++nt) {
            s8v bf = *(const s8v*)&BT_lds[(nt * 16 + l15) * 72 + koff];
            acc[nt] = __builtin_amdgcn_mfma_f32_16x16x32_bf16(af, bf, acc[nt], 0, 0, 0);
          }
        }
      }
      ush* dst = g_xw + ((size_t)t * 2 + gdir) * ((size_t)B_ * G4_);
#pragma unroll
      for (int nt = 0; nt < 8; ++nt) {
        int colg = nb * 128 + nt * 16 + l15;
        int g = colg >> 8, hc = colg & 255;
#pragma unroll
        for (int jj = 0; jj < 4; ++jj) {
          int row = w * 16 + (lq << 2) + jj;
          dst[(size_t)row * 1024 + hc * 4 + g] = f2b(acc[nt][jj]);
        }
      }
    }
  }
}

// ============================================================
// Dense [128,512]@[512,10] + bias + softmax -> out f32
// ============================================================
__global__ __launch_bounds__(512, 1) void dense_softmax(
    const float* __restrict__ Wd, const float* __restrict__ bd, float* __restrict__ out)
{
  __shared__ float wT[10 * 512];
  __shared__ float part[512 * 10];
  int tid = threadIdx.x;
  for (int i = tid; i < 5120; i += 512) {
    int k = i / 10, j = i - k * 10;
    wT[j * 512 + k] = Wd[i];
  }
  __syncthreads();
  int row = tid >> 2, q = tid & 3;
  float acc[10];
#pragma unroll
  for (int j = 0; j < 10; ++j) acc[j] = 0.f;
  const float* hrow = g_hT + (size_t)row * 512 + q * 128;
  for (int kk = 0; kk < 32; ++kk) {
    f32x4 h4 = *(const f32x4*)(hrow + kk * 4);
#pragma unroll
    for (int j = 0; j < 10; ++j) {
      f32x4 w4 = *(const f32x4*)&wT[j * 512 + q * 128 + kk * 4];
      acc[j] += h4[0] * w4[0] + h4[1] * w4[1] + h4[2] * w4[2] + h4[3] * w4[3];
    }
  }
#pragma unroll
  for (int j = 0; j < 10; ++j) part[tid * 10 + j] = acc[j];
  __syncthreads();
  if (tid < 128) {
    float lg[10];
#pragma unroll
    for (int j = 0; j < 10; ++j)
      lg[j] = bd[j] + part[(tid * 4 + 0) * 10 + j] + part[(tid * 4 + 1) * 10 + j]
                    + part[(tid * 4 + 2) * 10 + j] + part[(tid * 4 + 3) * 10 + j];
    float m = lg[0];
#pragma unroll
    for (int j = 1; j < 10; ++j) m = fmaxf(m, lg[j]);
    float ssum = 0.f;
#pragma unroll
    for (int j = 0; j < 10; ++j) { lg[j] = __expf(lg[j] - m); ssum += lg[j]; }
    float inv = 1.f / ssum;
#pragma unroll
    for (int j = 0; j < 10; ++j) out[tid * 10 + j] = lg[j] * inv;
  }
}

extern "C" void kernel_launch(void* const* d_in, const int* in_sizes, int n_in,
                              void* d_out, int out_size, void* d_ws, size_t ws_size,
                              hipStream_t stream) {
  (void)in_sizes; (void)n_in; (void)d_ws; (void)ws_size; (void)out_size;
  const int* x = (const int*)d_in[0];
  const float* emb = (const float*)d_in[1];
  const float* W1f = (const float*)d_in[2];
  const float* U1f = (const float*)d_in[3];
  const float* b1f = (const float*)d_in[4];
  const float* W1b = (const float*)d_in[5];
  const float* U1b = (const float*)d_in[6];
  const float* b1b = (const float*)d_in[7];
  const float* W2f = (const float*)d_in[8];
  const float* U2f = (const float*)d_in[9];
  const float* b2f = (const float*)d_in[10];
  const float* W2b = (const float*)d_in[11];
  const float* U2b = (const float*)d_in[12];
  const float* b2b = (const float*)d_in[13];
  const float* Wd  = (const float*)d_in[14];
  const float* bd  = (const float*)d_in[15];
  float* out = (float*)d_out;

  void* hx_p = nullptr; void* wt_p = nullptr; void* tc_p = nullptr;
  hipGetSymbolAddress(&hx_p, HIP_SYMBOL(g_hx2));
  hipGetSymbolAddress(&wt_p, HIP_SYMBOL(g_wtall));
  hipGetSymbolAddress(&tc_p, HIP_SYMBOL(g_tcnt));
  ush* wt = (ush*)wt_p;
  // seq values and counters must start at 0 every launch (graph replays!)
  hipMemsetAsync(hx_p, 0, sizeof(ull) * 16 * 2 * 2 * 2 * 512, stream);
  hipMemsetAsync(tc_p, 0, sizeof(unsigned) * 512, stream);

  ush* wt1f = wt;                 ush* wt1b = wt1f + 131072;   // K=128
  ush* ut1f = wt1b + 131072;      ush* ut1b = ut1f + 262144;   // K=256
  ush* wt2f = ut1b + 262144;      ush* wt2b = wt2f + 524288;   // K=512
  ush* ut2f = wt2b + 524288;      ush* ut2b = ut2f + 262144;   // K=256

  prep_w<<<dim3(32, 1, 2), 256, 0, stream>>>(W1f, W1b, wt1f, wt1b, 128);
  prep_w<<<dim3(64, 1, 2), 256, 0, stream>>>(U1f, U1b, ut1f, ut1b, 256);
  prep_w<<<dim3(128, 1, 2), 256, 0, stream>>>(W2f, W2b, wt2f, wt2b, 512);
  prep_w<<<dim3(64, 1, 2), 256, 0, stream>>>(U2f, U2b, ut2f, ut2b, 256);

  // layer 1 input projection (emb gather, K=128)
  gemm_xw<<<dim3(8, T_, 2), 512, 0, stream>>>(x, emb, wt1f, wt1b);
  // layer 1 recurrence + fused layer-2 input projection (192 gemm WGs)
  mega<<<256, 512, 0, stream>>>(0, ut1f, ut1b, b1f, b1b, 1, 192, wt2f, wt2b);
  // layer 2 recurrence
  mega<<<64, 512, 0, stream>>>(1, ut2f, ut2b, b2f, b2b, 0, 0, nullptr, nullptr);
  // dense + softmax
  dense_softmax<<<1, 512, 0, stream>>>(Wd, bd, out);
}